// Round 4
// baseline (318.929 us; speedup 1.0000x reference)
//
#include <hip/hip_runtime.h>
#include <stdint.h>

typedef __bf16 bf16x8 __attribute__((ext_vector_type(8)));
typedef float f32x4 __attribute__((ext_vector_type(4)));

__device__ __forceinline__ unsigned int f2bf(float f) {
  unsigned int u = __float_as_uint(f);
  return (u + 0x7fffu + ((u >> 16) & 1u)) >> 16;  // RNE
}
__device__ __forceinline__ unsigned int pack2(float a, float b) {
  return f2bf(a) | (f2bf(b) << 16);
}

// In-register 16-point FWHT (4 stages, unrolled)
__device__ __forceinline__ void fwht16(float v[16]) {
#pragma unroll
  for (int s = 0; s < 4; ++s) {
    const int h = 1 << s;
#pragma unroll
    for (int i = 0; i < 16; ++i) {
      if (!(i & h)) {
        float a = v[i], b = v[i ^ h];
        v[i] = a + b;
        v[i ^ h] = a - b;
      }
    }
  }
}

#define LP(i) ((i) + ((i) >> 5))  // padded LDS index

// ---------------------------------------------------------------------------
// K0: Xbf = bf16(x)  — pure stream, 8 elems/thread
// ---------------------------------------------------------------------------
__global__ void __launch_bounds__(256) k_cast(const float* __restrict__ X,
                                              unsigned short* __restrict__ Xb) {
  size_t i = (size_t)blockIdx.x * 2048 + (size_t)threadIdx.x * 8;
  float4 a = *(const float4*)(X + i);
  float4 b = *(const float4*)(X + i + 4);
  uint4 o;
  o.x = pack2(a.x, a.y);
  o.y = pack2(a.z, a.w);
  o.z = pack2(b.x, b.y);
  o.w = pack2(b.z, b.w);
  *(uint4*)(Xb + i) = o;
}

// ---------------------------------------------------------------------------
// K1: per W-row m: decompress 512 codes -> FWHT_k(4096)*(1/64) -> *SU[k] -> bf16
// (radix-16 register FWHT, 2 LDS exchanges — same structure as R3's k_fwht_in)
// ---------------------------------------------------------------------------
__global__ void __launch_bounds__(256) k_wrow(const int* __restrict__ Qidxs,
                                              const float* __restrict__ G,
                                              const float* __restrict__ SU,
                                              unsigned short* __restrict__ W) {
  __shared__ float lds[4224];
  const int t = threadIdx.x;
  const size_t m = blockIdx.x;
  int2 code = ((const int2*)(Qidxs + m * 512))[t];  // codes 2t, 2t+1 -> elems 16t..16t+15
  const float4* g0 = (const float4*)(G + (size_t)code.x * 8);
  const float4* g1 = (const float4*)(G + (size_t)code.y * 8);
  float4 c0 = g0[0], c1 = g0[1], c2 = g1[0], c3 = g1[1];
  float v[16] = {c0.x, c0.y, c0.z, c0.w, c1.x, c1.y, c1.z, c1.w,
                 c2.x, c2.y, c2.z, c2.w, c3.x, c3.y, c3.z, c3.w};
  fwht16(v);  // bits 0-3
#pragma unroll
  for (int q = 0; q < 4; ++q) {
    int i0 = 16 * t + 4 * q;
    *(float4*)&lds[LP(i0)] = make_float4(v[4 * q], v[4 * q + 1], v[4 * q + 2], v[4 * q + 3]);
  }
  __syncthreads();
  const int b = ((t >> 4) << 8) | (t & 15);
#pragma unroll
  for (int j = 0; j < 16; ++j) { int i = b + 16 * j; v[j] = lds[LP(i)]; }
  fwht16(v);  // bits 4-7
#pragma unroll
  for (int j = 0; j < 16; ++j) { int i = b + 16 * j; lds[LP(i)] = v[j]; }
  __syncthreads();
#pragma unroll
  for (int j = 0; j < 16; ++j) { int i = t + 256 * j; v[j] = lds[LP(i)]; }
  fwht16(v);  // bits 8-11
  unsigned short* orow = W + m * 4096;
#pragma unroll
  for (int j = 0; j < 16; ++j) {
    int i = t + 256 * j;
    orow[i] = (unsigned short)f2bf(v[j] * SU[i] * 0.015625f);
  }
}

// ---------------------------------------------------------------------------
// K2: H64 (unnormalized) over the m index, in place on bf16 W.
// H4096 = H64(high 6 bits) x H64(low 6 bits); two launches:
//   pass1: rows {64g..64g+63}   (base_per_group=64*4096, rstride=4096)
//   pass2: rows {g + 64j}       (base_per_group=4096,    rstride=64*4096)
// One k-column per thread: all global access lane-contiguous (coalesced).
// The 1/64 normalization is folded into the GEMM's SV epilogue.
// ---------------------------------------------------------------------------
__global__ void __launch_bounds__(256) k_wm(unsigned short* __restrict__ W,
                                            int base_per_group, int rstride) {
  const int col = blockIdx.x * 256 + threadIdx.x;
  const int base = blockIdx.y * base_per_group + col;
  float v[64];
#pragma unroll
  for (int r = 0; r < 64; ++r) {
    unsigned int u = W[base + r * rstride];
    v[r] = __uint_as_float(u << 16);
  }
#pragma unroll
  for (int s = 0; s < 6; ++s) {
    const int h = 1 << s;
#pragma unroll
    for (int i = 0; i < 64; ++i) {
      if (!(i & h)) {
        float a = v[i], b = v[i ^ h];
        v[i] = a + b;
        v[i ^ h] = a - b;
      }
    }
  }
#pragma unroll
  for (int r = 0; r < 64; ++r)
    W[base + r * rstride] = (unsigned short)f2bf(v[r]);
}

// ---------------------------------------------------------------------------
// K3: GEMM C = A @ Bt^T (bf16 [4096][4096], K-major), fp32 out, *SV*(1/64).
// m97 recipe + XOR swizzle on the GLOBAL address (R2: conflicts 5e7 -> 0).
// ---------------------------------------------------------------------------
__device__ __forceinline__ void gl2lds16(const unsigned short* g, unsigned short* l) {
  __builtin_amdgcn_global_load_lds(
      (const __attribute__((address_space(1))) void*)g,
      (__attribute__((address_space(3))) void*)l, 16, 0, 0);
}

__global__ void __launch_bounds__(256) k_gemm_bt(const unsigned short* __restrict__ A,
                                                 const unsigned short* __restrict__ B,
                                                 const float* __restrict__ SV,
                                                 float* __restrict__ C) {
  const int K = 4096, N = 4096;
  __shared__ unsigned short sA[128 * 64];
  __shared__ unsigned short sB[128 * 64];
  const int tid = threadIdx.x;
  const int wave = tid >> 6, lane = tid & 63;
  const int bn = blockIdx.x, bm = blockIdx.y;
  const int wr = wave >> 1, wc = wave & 1;
  const int frow = lane & 15;
  const int sw = frow & 7;
  const int jbase = lane >> 4;
  f32x4 acc[4][4] = {};

  const size_t rowA0 = (size_t)bm * 128;
  const size_t rowB0 = (size_t)bn * 128;

  for (int kt = 0; kt < K; kt += 64) {
    __syncthreads();
#pragma unroll
    for (int it = 0; it < 4; ++it) {
      int c = it * 256 + tid;
      int r = c >> 3;
      int jg = (c & 7) ^ (r & 7);
      int kc = jg * 8;
      unsigned short* la = &sA[(it * 256 + wave * 64) * 8];
      unsigned short* lb = &sB[(it * 256 + wave * 64) * 8];
      gl2lds16(A + (rowA0 + r) * K + kt + kc, la);
      gl2lds16(B + (rowB0 + r) * K + kt + kc, lb);
    }
    __syncthreads();
#pragma unroll
    for (int kk = 0; kk < 64; kk += 32) {
      bf16x8 af[4], bfr[4];
      int jn = (kk >> 3) + jbase;
      int js = jn ^ sw;
#pragma unroll
      for (int i = 0; i < 4; ++i)
        af[i] = *(const bf16x8*)&sA[(wr * 64 + i * 16 + frow) * 64 + js * 8];
#pragma unroll
      for (int j = 0; j < 4; ++j)
        bfr[j] = *(const bf16x8*)&sB[(wc * 64 + j * 16 + frow) * 64 + js * 8];
#pragma unroll
      for (int i = 0; i < 4; ++i)
#pragma unroll
        for (int j = 0; j < 4; ++j)
          acc[i][j] = __builtin_amdgcn_mfma_f32_16x16x32_bf16(af[i], bfr[j], acc[i][j], 0, 0, 0);
    }
  }
  const int crow = bm * 128 + wr * 64 + (lane >> 4) * 4;
  const int ccol = bn * 128 + wc * 64 + (lane & 15);
  float sv[4];
#pragma unroll
  for (int j = 0; j < 4; ++j) sv[j] = SV[ccol + 16 * j] * 0.015625f;  // 1/64 of H_m
#pragma unroll
  for (int i = 0; i < 4; ++i)
#pragma unroll
    for (int j = 0; j < 4; ++j) {
      float* cp = C + (size_t)(crow + i * 16) * N + ccol + j * 16;
#pragma unroll
      for (int r = 0; r < 4; ++r) cp[(size_t)r * N] = acc[i][j][r] * sv[j];
    }
}

// ---------------------------------------------------------------------------
extern "C" void kernel_launch(void* const* d_in, const int* in_sizes, int n_in,
                              void* d_out, int out_size, void* d_ws, size_t ws_size,
                              hipStream_t stream) {
  const float* X     = (const float*)d_in[0];
  const float* SU    = (const float*)d_in[1];
  const float* SV    = (const float*)d_in[2];
  const float* G     = (const float*)d_in[3];
  const int*   Qidxs = (const int*)d_in[4];
  float* out = (float*)d_out;

  unsigned short* Xb = (unsigned short*)d_ws;       // 32 MB
  unsigned short* Wh = Xb + (size_t)4096 * 4096;    // 32 MB

  k_cast<<<8192, 256, 0, stream>>>(X, Xb);
  k_wrow<<<4096, 256, 0, stream>>>(Qidxs, G, SU, Wh);
  k_wm<<<dim3(16, 64), 256, 0, stream>>>(Wh, 64 * 4096, 4096);   // low 6 bits of m
  k_wm<<<dim3(16, 64), 256, 0, stream>>>(Wh, 4096, 64 * 4096);   // high 6 bits of m
  k_gemm_bt<<<dim3(32, 32), 256, 0, stream>>>(Xb, Wh, SV, out);
}